// Round 10
// baseline (376.141 us; speedup 1.0000x reference)
//
#include <hip/hip_runtime.h>
#include <hip/hip_fp16.h>
#include <stdint.h>

#define HIDDEN 4096
#define FFN    14336
#define MDIM   512
#define G1     224   // FFN / 64
#define G2     64    // HIDDEN / 64
#define BK     128
#define KB_H   128   // HIDDEN/32
#define KB_F   448   // FFN/32

typedef _Float16 f16x8 __attribute__((ext_vector_type(8)));
typedef float f32x4 __attribute__((ext_vector_type(4)));

#define SCHED0() __builtin_amdgcn_sched_barrier(0);
#define LGKM_BAR()                                            \
    asm volatile("s_waitcnt lgkmcnt(0)" ::: "memory");        \
    __builtin_amdgcn_s_barrier();                             \
    __builtin_amdgcn_sched_barrier(0);

// ---------------- prep kernels ----------------

// x (f32, row-major) -> xbp (f16, MFMA-fragment-major):
// xbp[((mb*KB_H + kb)*64 + lane)*8 + e] = x[mb*16 + (lane&15)][kb*32 + (lane>>4)*8 + e]
__global__ void cvt_xp_kernel(const float* __restrict__ x, ushort* __restrict__ xbp) {
    int i = blockIdx.x * blockDim.x + threadIdx.x;   // [0, MDIM*HIDDEN/8)
    int ls = i & 63;
    int kb = (i >> 6) & (KB_H - 1);
    int mb = i >> 13;
    int row = mb * 16 + (ls & 15);
    int col = kb * 32 + (ls >> 4) * 8;
    const float4* src = (const float4*)&x[(size_t)row * HIDDEN + col];
    float4 v0 = src[0], v1 = src[1];
    __half2 h0 = __floats2half2_rn(v0.x, v0.y);
    __half2 h1 = __floats2half2_rn(v0.z, v0.w);
    __half2 h2 = __floats2half2_rn(v1.x, v1.y);
    __half2 h3 = __floats2half2_rn(v1.z, v1.w);
    uint4 o = make_uint4(__builtin_bit_cast(uint32_t, h0), __builtin_bit_cast(uint32_t, h1),
                         __builtin_bit_cast(uint32_t, h2), __builtin_bit_cast(uint32_t, h3));
    ((uint4*)xbp)[i] = o;
}

// out[2i] = {f16(s0), f16(s1)}, out[2i+1] = {f16(-z0*s0), f16(-z1*s1)}
__global__ void build_sz_kernel(const float* __restrict__ s, const float* __restrict__ z,
                                uint32_t* __restrict__ outp) {
    int i = blockIdx.x * blockDim.x + threadIdx.x;
    float s0 = s[2 * i], s1 = s[2 * i + 1];
    float z0 = z[2 * i], z1 = z[2 * i + 1];
    __half2 hs = __floats2half2_rn(s0, s1);
    __half2 hn = __floats2half2_rn(-z0 * s0, -z1 * s1);
    ((uint2*)outp)[i] = make_uint2(__builtin_bit_cast(uint32_t, hs),
                                   __builtin_bit_cast(uint32_t, hn));
}

// dequant 2 codes -> packed f16 pair: table-select via v_perm + v_pk_fma_f16
__device__ __forceinline__ uint32_t deq2(uint32_t w0, uint32_t w1, uint32_t sh,
                                         uint32_t spair, uint32_t npair) {
    uint32_t c0 = (w0 >> sh) & 3u;
    uint32_t c1 = (w1 >> sh) & 3u;
    uint32_t sel = 0x01000100u + c0 * 0x0202u + c1 * 0x02020000u;
    uint32_t codes = __builtin_amdgcn_perm(0x42004000u, 0x3C000000u, sel); // f16{0,1,2,3}
    __half2 r = __hfma2(__builtin_bit_cast(__half2, codes),
                        __builtin_bit_cast(__half2, spair),
                        __builtin_bit_cast(__half2, npair));
    return __builtin_bit_cast(uint32_t, r);
}

// dequant 16 consecutive k for one row: wv[16] codes, zva[4] packed sz, -> 4 uint4 stores
__device__ __forceinline__ void deq_row16(const uint32_t* wv, const uint4* zva, uint32_t sh,
                                          ushort* dst0, ushort* dst1) {
    uint32_t o[8];
#pragma unroll
    for (int j = 0; j < 8; ++j) {
        uint32_t sp = (j & 1) ? zva[j >> 1].z : zva[j >> 1].x;
        uint32_t np = (j & 1) ? zva[j >> 1].w : zva[j >> 1].y;
        o[j] = deq2(wv[2 * j], wv[2 * j + 1], sh, sp, np);
    }
    *(uint4*)dst0 = make_uint4(o[0], o[1], o[2], o[3]);
    *(uint4*)dst1 = make_uint4(o[4], o[5], o[6], o[7]);
}

// ---------------- GEMM A: gate/up fused + SwiGLU -> hp (f16 frag-major) ----------------
// BM=256, BN=32, BK=128, 4 waves M-stacked (wave 64x32). A: frag-major global->reg,
// rotating per-kk loads. B: reg 1-step prefetch -> dequant -> dbuf LDS. 32 steps.

__global__ __launch_bounds__(256, 2)
void gemm_gateup(const ushort* __restrict__ xbp, const uint32_t* __restrict__ qw1,
                 const uint32_t* __restrict__ sz1, const uint32_t* __restrict__ qw3,
                 const uint32_t* __restrict__ sz3, ushort* __restrict__ hp) {
    __shared__ ushort sB1[2][32 * 128];   // 16 KB
    __shared__ ushort sB2[2][32 * 128];   // 16 KB
    __shared__ ushort sE[256 * 32];       // 16 KB epilogue staging

    const int tid = threadIdx.x;
    // XCD swizzle: 896 = 8 x 112; mt fast
    const int idx = ((blockIdx.x & 7) * 112) + (blockIdx.x >> 3);
    const int mt = idx & 1, nt = idx >> 1;
    const int m0 = mt * 256, n0 = nt * 32;

    const int lane = tid & 63, w = tid >> 6;
    const int wm = w * 64;
    const int frow = lane & 15, fk = (lane >> 4) * 8;
    const int sw = (frow & 7) << 3;       // B read-side XOR swizzle

    uint32_t abase[4];
#pragma unroll
    for (int mi = 0; mi < 4; ++mi)
        abase[mi] = (uint32_t)(((m0 >> 4) + w * 4 + mi) * KB_H) * 512 + lane * 8;

    // B staging: threads 0-127 gate, 128-255 up; 2 rows x 16 k each
    const int bi = tid & 127;
    const int rp = bi >> 3;                       // 0..15 row-pair
    const int kc = (bi & 7) * 16;                 // 16-wide k chunk
    const int row0 = rp * 2;
    const int g0 = (n0 + row0) % G1;              // even, <=222; g0+1 no wrap
    const uint32_t* qp = (tid < 128 ? qw1 : qw3) + (size_t)(n0 / 4 + (rp >> 1)) * HIDDEN + kc;
    const uint32_t* zp = (tid < 128 ? sz1 : sz3) + (size_t)g0 * HIDDEN + kc;
    ushort (*sB)[32 * 128] = (tid < 128) ? sB1 : sB2;
    const uint32_t sh0 = 6u - 4u * (uint32_t)(rp & 1);
    const int wc0 = row0 * 128 + (kc ^ ((row0 & 7) << 3));
    const int wc1 = row0 * 128 + ((kc + 8) ^ ((row0 & 7) << 3));
    const int wc2 = (row0 + 1) * 128 + (kc ^ (((row0 + 1) & 7) << 3));
    const int wc3 = (row0 + 1) * 128 + ((kc + 8) ^ (((row0 + 1) & 7) << 3));

    f32x4 accG[4][2], accU[4][2];
#pragma unroll
    for (int i = 0; i < 4; ++i)
#pragma unroll
        for (int j = 0; j < 2; ++j) {
            accG[i][j] = (f32x4){0.f, 0.f, 0.f, 0.f};
            accU[i][j] = (f32x4){0.f, 0.f, 0.f, 0.f};
        }

    f16x8 afE[4], afO[4];                 // A-frag rotating sets (even/odd kk)
    uint4 qv0, qv1, qv2, qv3;             // qw: 16 words
    uint4 zv0, zv1, zv2, zv3;             // sz row0: 16 words
    uint4 zv4, zv5, zv6, zv7;             // sz row1: 16 words

#define GU_LDA(AF, kbidx)                                                      \
    { _Pragma("unroll")                                                        \
      for (int mi = 0; mi < 4; ++mi)                                           \
          AF[mi] = *(const f16x8*)&xbp[abase[mi] + (uint32_t)(kbidx) * 512]; }

#define GU_LDQZ(k0q)                                                           \
    qv0 = *(const uint4*)(qp + (k0q));      qv1 = *(const uint4*)(qp + (k0q) + 4);  \
    qv2 = *(const uint4*)(qp + (k0q) + 8);  qv3 = *(const uint4*)(qp + (k0q) + 12); \
    zv0 = *(const uint4*)(zp + (k0q));      zv1 = *(const uint4*)(zp + (k0q) + 4);  \
    zv2 = *(const uint4*)(zp + (k0q) + 8);  zv3 = *(const uint4*)(zp + (k0q) + 12); \
    zv4 = *(const uint4*)(zp + HIDDEN + (k0q));      zv5 = *(const uint4*)(zp + HIDDEN + (k0q) + 4); \
    zv6 = *(const uint4*)(zp + HIDDEN + (k0q) + 8);  zv7 = *(const uint4*)(zp + HIDDEN + (k0q) + 12);

#define GU_DEQ(wbuf)                                                           \
    { const uint32_t wv[16] = {qv0.x, qv0.y, qv0.z, qv0.w, qv1.x, qv1.y, qv1.z, qv1.w, \
                               qv2.x, qv2.y, qv2.z, qv2.w, qv3.x, qv3.y, qv3.z, qv3.w}; \
      { const uint4 zva[4] = {zv0, zv1, zv2, zv3};                             \
        deq_row16(wv, zva, sh0, &sB[wbuf][wc0], &sB[wbuf][wc1]); }             \
      { const uint4 zva[4] = {zv4, zv5, zv6, zv7};                             \
        deq_row16(wv, zva, sh0 - 2u, &sB[wbuf][wc2], &sB[wbuf][wc3]); } }

#define GU_MFMA_KK(AF, rbuf, kk)                                               \
    { const int col = ((kk) * 32 + fk) ^ sw;                                   \
      f16x8 bg0 = *(const f16x8*)&sB1[rbuf][frow * 128 + col];                 \
      f16x8 bg1 = *(const f16x8*)&sB1[rbuf][(16 + frow) * 128 + col];          \
      f16x8 bu0 = *(const f16x8*)&sB2[rbuf][frow * 128 + col];                 \
      f16x8 bu1 = *(const f16x8*)&sB2[rbuf][(16 + frow) * 128 + col];          \
      _Pragma("unroll")                                                        \
      for (int mi = 0; mi < 4; ++mi) {                                         \
          accG[mi][0] = __builtin_amdgcn_mfma_f32_16x16x32_f16(AF[mi], bg0, accG[mi][0], 0, 0, 0); \
          accG[mi][1] = __builtin_amdgcn_mfma_f32_16x16x32_f16(AF[mi], bg1, accG[mi][1], 0, 0, 0); \
          accU[mi][0] = __builtin_amdgcn_mfma_f32_16x16x32_f16(AF[mi], bu0, accU[mi][0], 0, 0, 0); \
          accU[mi][1] = __builtin_amdgcn_mfma_f32_16x16x32_f16(AF[mi], bu1, accU[mi][1], 0, 0, 0); \
      } }

// afE must hold (tcur, kk0) on entry; if DON, leaves afE = (tcur+1, kk0)
#define GU_COMP(tcur, rbuf, DON)                                               \
    { GU_LDA(afO, (tcur) * 4 + 1)                                              \
      GU_MFMA_KK(afE, rbuf, 0)                                                 \
      GU_LDA(afE, (tcur) * 4 + 2)                                              \
      GU_MFMA_KK(afO, rbuf, 1)                                                 \
      GU_LDA(afO, (tcur) * 4 + 3)                                              \
      GU_MFMA_KK(afE, rbuf, 2)                                                 \
      if (DON) { GU_LDA(afE, (tcur) * 4 + 4) }                                 \
      GU_MFMA_KK(afO, rbuf, 3) }

    // prologue: afE=(0,kk0); tile0 regs -> DEQ buf0; tile1 regs in flight
    GU_LDA(afE, 0)
    GU_LDQZ(0)
    GU_DEQ(0)
    SCHED0()
    GU_LDQZ(BK)
    LGKM_BAR()

    for (int t = 0; t < 31; ++t) {
        GU_DEQ((t + 1) & 1)                       // tile t+1 (waits its reg loads)
        SCHED0()
        if (t <= 29) { GU_LDQZ((t + 2) * BK) }    // tile t+2 into same regs (WAR)
        SCHED0()
        GU_COMP(t, t & 1, 1)
        LGKM_BAR()
    }
    GU_COMP(31, 1, 0)

    // ---- epilogue: silu(gate)*up -> sE -> frag-major stores to hp ----
    const int rb = (lane >> 4) * 4, cb = lane & 15;
#pragma unroll
    for (int mi = 0; mi < 4; ++mi)
#pragma unroll
        for (int ni = 0; ni < 2; ++ni) {
            f32x4 g = accG[mi][ni], u = accU[mi][ni];
            const int row = wm + mi * 16 + rb;
            const int colx = ni * 16 + cb;
#pragma unroll
            for (int r = 0; r < 4; ++r) {
                float gv = g[r];
                float hv = __fdividef(gv, 1.0f + __expf(-gv)) * u[r];
                __half hh = __float2half(hv);
                sE[(row + r) * 32 + colx] = __builtin_bit_cast(ushort, hh);
            }
        }
    __syncthreads();
    {
#pragma unroll
        for (int j = 0; j < 4; ++j) {
            const int slot = tid + j * 256;
            const int mbi = slot >> 6, ls = slot & 63;
            uint4 v = *(const uint4*)&sE[(mbi * 16 + (ls & 15)) * 32 + (ls >> 4) * 8];
            *(uint4*)&hp[(size_t)(((m0 >> 4) + mbi) * KB_F + nt) * 512 + ls * 8] = v;
        }
    }
#undef GU_LDA
#undef GU_LDQZ
#undef GU_DEQ
#undef GU_MFMA_KK
#undef GU_COMP
}

// ---------------- GEMM B: out_partial = hp @ w2^T (split-K = 2) ----------------
// BM=256, BN=32, BK=128; 56 steps per half; A frag-major rotating; B dbuf LDS.

__global__ __launch_bounds__(256, 3)
void gemm_down(const ushort* __restrict__ hp, const uint32_t* __restrict__ qw2,
               const uint32_t* __restrict__ sz2, float* __restrict__ part) {
    __shared__ ushort sBd[2][32 * 128];   // 16 KB

    const int tid = threadIdx.x;
    // 512 = 8 x 64 XCD swizzle
    const int idx = ((blockIdx.x & 7) * 64) + (blockIdx.x >> 3);
    const int mt = idx & 1, nt = (idx >> 1) & 127, sk = idx >> 8;
    const int m0 = mt * 256, n0 = nt * 32;
    const int kb0 = sk * 224;             // kbeg/32
    const int kbeg = sk * (FFN / 2);

    const int lane = tid & 63, w = tid >> 6;
    const int wm = w * 64;
    const int frow = lane & 15, fk = (lane >> 4) * 8;
    const int sw = (frow & 7) << 3;

    uint32_t abase[4];
#pragma unroll
    for (int mi = 0; mi < 4; ++mi)
        abase[mi] = (uint32_t)(((m0 >> 4) + w * 4 + mi) * KB_F + kb0) * 512 + lane * 8;

    // B staging: 1 row x 16 k per thread (32 rows x 8 chunks = 256)
    const int r = tid >> 3;               // 0..31
    const int kc = (tid & 7) * 16;
    const int g = ((nt & 1) * 32) + r;    // (n0 + r) % 64
    const uint32_t* qp = qw2 + (size_t)(n0 / 4 + (r >> 2)) * FFN + kbeg + kc;
    const uint32_t* zp = sz2 + (size_t)g * FFN + kbeg + kc;
    const uint32_t sh = 6u - 2u * (uint32_t)(r & 3);
    const int wc0 = r * 128 + (kc ^ ((r & 7) << 3));
    const int wc1 = r * 128 + ((kc + 8) ^ ((r & 7) << 3));

    f32x4 acc[4][2];
#pragma unroll
    for (int i = 0; i < 4; ++i)
#pragma unroll
        for (int j = 0; j < 2; ++j) acc[i][j] = (f32x4){0.f, 0.f, 0.f, 0.f};

    f16x8 afE[4], afO[4];
    uint4 qv0, qv1, qv2, qv3;
    uint4 zv0, zv1, zv2, zv3;

#define GD_LDA(AF, kbidx)                                                      \
    { _Pragma("unroll")                                                        \
      for (int mi = 0; mi < 4; ++mi)                                           \
          AF[mi] = *(const f16x8*)&hp[abase[mi] + (uint32_t)(kbidx) * 512]; }

#define GD_LDQZ(k0q)                                                           \
    qv0 = *(const uint4*)(qp + (k0q));      qv1 = *(const uint4*)(qp + (k0q) + 4);  \
    qv2 = *(const uint4*)(qp + (k0q) + 8);  qv3 = *(const uint4*)(qp + (k0q) + 12); \
    zv0 = *(const uint4*)(zp + (k0q));      zv1 = *(const uint4*)(zp + (k0q) + 4);  \
    zv2 = *(const uint4*)(zp + (k0q) + 8);  zv3 = *(const uint4*)(zp + (k0q) + 12);

#define GD_DEQ(wbuf)                                                           \
    { const uint32_t wv[16] = {qv0.x, qv0.y, qv0.z, qv0.w, qv1.x, qv1.y, qv1.z, qv1.w, \
                               qv2.x, qv2.y, qv2.z, qv2.w, qv3.x, qv3.y, qv3.z, qv3.w}; \
      const uint4 zva[4] = {zv0, zv1, zv2, zv3};                               \
      deq_row16(wv, zva, sh, &sBd[wbuf][wc0], &sBd[wbuf][wc1]); }

#define GD_MFMA_KK(AF, rbuf, kk)                                               \
    { const int col = ((kk) * 32 + fk) ^ sw;                                   \
      f16x8 bf0 = *(const f16x8*)&sBd[rbuf][frow * 128 + col];                 \
      f16x8 bf1 = *(const f16x8*)&sBd[rbuf][(16 + frow) * 128 + col];          \
      _Pragma("unroll")                                                        \
      for (int mi = 0; mi < 4; ++mi) {                                         \
          acc[mi][0] = __builtin_amdgcn_mfma_f32_16x16x32_f16(AF[mi], bf0, acc[mi][0], 0, 0, 0); \
          acc[mi][1] = __builtin_amdgcn_mfma_f32_16x16x32_f16(AF[mi], bf1, acc[mi][1], 0, 0, 0); \
      } }

#define GD_COMP(tcur, rbuf, DON)                                               \
    { GD_LDA(afO, (tcur) * 4 + 1)                                              \
      GD_MFMA_KK(afE, rbuf, 0)                                                 \
      GD_LDA(afE, (tcur) * 4 + 2)                                               \
      GD_MFMA_KK(afO, rbuf, 1)                                                 \
      GD_LDA(afO, (tcur) * 4 + 3)                                              \
      GD_MFMA_KK(afE, rbuf, 2)                                                 \
      if (DON) { GD_LDA(afE, (tcur) * 4 + 4) }                                 \
      GD_MFMA_KK(afO, rbuf, 3) }

    GD_LDA(afE, 0)
    GD_LDQZ(0)
    GD_DEQ(0)
    SCHED0()
    GD_LDQZ(BK)
    LGKM_BAR()

    for (int t = 0; t < 55; ++t) {
        GD_DEQ((t + 1) & 1)
        SCHED0()
        if (t <= 53) { GD_LDQZ((t + 2) * BK) }
        SCHED0()
        GD_COMP(t, t & 1, 1)
        LGKM_BAR()
    }
    GD_COMP(55, 1, 0)

    float* pp = part + (size_t)sk * MDIM * HIDDEN;
    const int rb = (lane >> 4) * 4, cb = lane & 15;
#pragma unroll
    for (int mi = 0; mi < 4; ++mi)
#pragma unroll
        for (int ni = 0; ni < 2; ++ni) {
            f32x4 a = acc[mi][ni];
            const int mm = m0 + wm + mi * 16 + rb;
            const int nn = n0 + ni * 16 + cb;
#pragma unroll
            for (int rr = 0; rr < 4; ++rr) pp[(size_t)(mm + rr) * HIDDEN + nn] = a[rr];
        }
#undef GD_LDA
#undef GD_LDQZ
#undef GD_DEQ
#undef GD_MFMA_KK
#undef GD_COMP
}

// ---------------- reduce split-K partials ----------------

__global__ void reduce_out(const float* __restrict__ part, float* __restrict__ out) {
    int i = blockIdx.x * blockDim.x + threadIdx.x;
    const int Q = MDIM * HIDDEN / 4;
    float4 a = ((const float4*)part)[i];
    float4 b = ((const float4*)part)[i + Q];
    float4 o;
    o.x = a.x + b.x; o.y = a.y + b.y; o.z = a.z + b.z; o.w = a.w + b.w;
    ((float4*)out)[i] = o;
}

// ---------------- launch ----------------

extern "C" void kernel_launch(void* const* d_in, const int* in_sizes, int n_in,
                              void* d_out, int out_size, void* d_ws, size_t ws_size,
                              hipStream_t stream) {
    (void)in_sizes; (void)n_in; (void)out_size; (void)ws_size;

    const float* x  = (const float*)d_in[0];
    const uint32_t* qw1 = (const uint32_t*)d_in[1];
    const float* s1 = (const float*)d_in[2];
    const float* z1 = (const float*)d_in[3];
    const uint32_t* qw3 = (const uint32_t*)d_in[4];
    const float* s3 = (const float*)d_in[5];
    const float* z3 = (const float*)d_in[6];
    const uint32_t* qw2 = (const uint32_t*)d_in[7];
    const float* s2 = (const float*)d_in[8];
    const float* z2 = (const float*)d_in[9];
    float* out = (float*)d_out;

    // ws: xbp 4.19M | sz1 3.67M | sz3 3.67M | sz2 3.67M | hp(f16) 14.68M | part 16.78M
    char* ws = (char*)d_ws;
    ushort*   xbp  = (ushort*)ws;
    uint32_t* szp1 = (uint32_t*)(ws + (size_t)MDIM * HIDDEN * 2);
    uint32_t* szp3 = szp1 + (size_t)G1 * HIDDEN;
    uint32_t* szp2 = szp3 + (size_t)G1 * HIDDEN;
    ushort*   hp   = (ushort*)(szp2 + (size_t)G2 * FFN);
    float*    part = (float*)((char*)hp + (size_t)MDIM * FFN * 2);

    cvt_xp_kernel<<<(MDIM * HIDDEN / 8) / 256, 256, 0, stream>>>(x, xbp);
    build_sz_kernel<<<(G1 * HIDDEN / 2) / 256, 256, 0, stream>>>(s1, z1, szp1);
    build_sz_kernel<<<(G1 * HIDDEN / 2) / 256, 256, 0, stream>>>(s3, z3, szp3);
    build_sz_kernel<<<(G2 * FFN / 2) / 256, 256, 0, stream>>>(s2, z2, szp2);

    gemm_gateup<<<(FFN / 32) * (MDIM / 256), 256, 0, stream>>>(xbp, qw1, szp1, qw3, szp3, hp);
    gemm_down<<<2 * (MDIM / 256) * (HIDDEN / 32), 256, 0, stream>>>(hp, qw2, szp2, part);
    reduce_out<<<(MDIM * HIDDEN / 4) / 256, 256, 0, stream>>>(part, out);
}

// Round 11
// 329.697 us; speedup vs baseline: 1.1409x; 1.1409x over previous
//
#include <hip/hip_runtime.h>
#include <hip/hip_fp16.h>
#include <stdint.h>

#define HIDDEN 4096
#define FFN    14336
#define MDIM   512
#define G1     224   // FFN / 64
#define G2     64    // HIDDEN / 64
#define BK     64
#define KB_H   128   // HIDDEN/32
#define KB_F   448   // FFN/32

typedef _Float16 f16x8 __attribute__((ext_vector_type(8)));
typedef float f32x4 __attribute__((ext_vector_type(4)));

#define SCHED0() __builtin_amdgcn_sched_barrier(0);
#define LGKM_BAR()                                            \
    asm volatile("s_waitcnt lgkmcnt(0)" ::: "memory");        \
    __builtin_amdgcn_s_barrier();                             \
    __builtin_amdgcn_sched_barrier(0);

// ---------------- prep kernels ----------------

// x (f32, row-major) -> xbp (f16, MFMA-fragment-major):
// xbp[((mb*KB_H + kb)*64 + lane)*8 + e] = x[mb*16 + (lane&15)][kb*32 + (lane>>4)*8 + e]
__global__ void cvt_xp_kernel(const float* __restrict__ x, ushort* __restrict__ xbp) {
    int i = blockIdx.x * blockDim.x + threadIdx.x;   // [0, MDIM*HIDDEN/8)
    int ls = i & 63;
    int kb = (i >> 6) & (KB_H - 1);
    int mb = i >> 13;
    int row = mb * 16 + (ls & 15);
    int col = kb * 32 + (ls >> 4) * 8;
    const float4* src = (const float4*)&x[(size_t)row * HIDDEN + col];
    float4 v0 = src[0], v1 = src[1];
    __half2 h0 = __floats2half2_rn(v0.x, v0.y);
    __half2 h1 = __floats2half2_rn(v0.z, v0.w);
    __half2 h2 = __floats2half2_rn(v1.x, v1.y);
    __half2 h3 = __floats2half2_rn(v1.z, v1.w);
    uint4 o = make_uint4(__builtin_bit_cast(uint32_t, h0), __builtin_bit_cast(uint32_t, h1),
                         __builtin_bit_cast(uint32_t, h2), __builtin_bit_cast(uint32_t, h3));
    ((uint4*)xbp)[i] = o;
}

// out[2i] = {f16(s0), f16(s1)}, out[2i+1] = {f16(-z0*s0), f16(-z1*s1)}
__global__ void build_sz_kernel(const float* __restrict__ s, const float* __restrict__ z,
                                uint32_t* __restrict__ outp) {
    int i = blockIdx.x * blockDim.x + threadIdx.x;
    float s0 = s[2 * i], s1 = s[2 * i + 1];
    float z0 = z[2 * i], z1 = z[2 * i + 1];
    __half2 hs = __floats2half2_rn(s0, s1);
    __half2 hn = __floats2half2_rn(-z0 * s0, -z1 * s1);
    ((uint2*)outp)[i] = make_uint2(__builtin_bit_cast(uint32_t, hs),
                                   __builtin_bit_cast(uint32_t, hn));
}

// dequant 2 codes -> packed f16 pair: table-select via v_perm + v_pk_fma_f16
__device__ __forceinline__ uint32_t deq2(uint32_t w0, uint32_t w1, uint32_t sh,
                                         uint32_t spair, uint32_t npair) {
    uint32_t c0 = (w0 >> sh) & 3u;
    uint32_t c1 = (w1 >> sh) & 3u;
    uint32_t sel = 0x01000100u + c0 * 0x0202u + c1 * 0x02020000u;
    uint32_t codes = __builtin_amdgcn_perm(0x42004000u, 0x3C000000u, sel); // f16{0,1,2,3}
    __half2 r = __hfma2(__builtin_bit_cast(__half2, codes),
                        __builtin_bit_cast(__half2, spair),
                        __builtin_bit_cast(__half2, npair));
    return __builtin_bit_cast(uint32_t, r);
}

// ---------------- GEMM A: gate/up fused + SwiGLU -> hp (f16 frag-major) ----------------
// BM=256, BN=32, BK=64, 4 waves M-stacked (wave 64x32). Lean registers:
// A half-set rotation (tile-granularity lookahead), single qw/sz set, T5 setprio.

__global__ __launch_bounds__(256, 3)
void gemm_gateup(const ushort* __restrict__ xbp, const uint32_t* __restrict__ qw1,
                 const uint32_t* __restrict__ sz1, const uint32_t* __restrict__ qw3,
                 const uint32_t* __restrict__ sz3, ushort* __restrict__ hp) {
    __shared__ ushort sB1[2][32 * 64];    // 8 KB
    __shared__ ushort sB2[2][32 * 64];    // 8 KB
    __shared__ ushort sE[256 * 32];       // 16 KB epilogue staging

    const int tid = threadIdx.x;
    // XCD swizzle: 896 = 8 x 112; mt fast
    const int idx = ((blockIdx.x & 7) * 112) + (blockIdx.x >> 3);
    const int mt = idx & 1, nt = idx >> 1;
    const int m0 = mt * 256, n0 = nt * 32;

    const int lane = tid & 63, w = tid >> 6;
    const int wm = w * 64;
    const int frow = lane & 15, fk = (lane >> 4) * 8;
    const int sw = (frow & 7) << 3;       // B read-side XOR swizzle

    uint32_t abase[4];
#pragma unroll
    for (int mi = 0; mi < 4; ++mi)
        abase[mi] = (uint32_t)(((m0 >> 4) + w * 4 + mi) * KB_H) * 512 + lane * 8;

    // B staging: threads 0-127 gate, 128-255 up; 2 rows x 8 k each
    const int bi = tid & 127;
    const int rp = bi >> 3;
    const int kc = (bi & 7) * 8;
    const int row0 = rp * 2;
    const int g0 = (n0 + row0) % G1;      // even, <=222; g0+1 no wrap
    const uint32_t* qp = (tid < 128 ? qw1 : qw3) + (size_t)(n0 / 4 + (rp >> 1)) * HIDDEN + kc;
    const uint32_t* zp = (tid < 128 ? sz1 : sz3) + (size_t)g0 * HIDDEN + kc;
    ushort (*sB)[32 * 64] = (tid < 128) ? sB1 : sB2;
    const uint32_t sh0 = 6u - 4u * (uint32_t)(rp & 1);
    const int wc0 = row0 * 64 + (kc ^ ((row0 & 7) << 3));
    const int wc1 = (row0 + 1) * 64 + (kc ^ (((row0 + 1) & 7) << 3));

    f32x4 accG[4][2], accU[4][2];
#pragma unroll
    for (int i = 0; i < 4; ++i)
#pragma unroll
        for (int j = 0; j < 2; ++j) {
            accG[i][j] = (f32x4){0.f, 0.f, 0.f, 0.f};
            accU[i][j] = (f32x4){0.f, 0.f, 0.f, 0.f};
        }

    f16x8 afE[4], afO[4];                 // A-frag half-sets (kk0 / kk1)
    uint4 pw0, pw1, pz0, pz1, pz2, pz3;   // single qw/sz set (1-step lookahead)

#define GU_LDAE(tt)                                                            \
    { _Pragma("unroll")                                                        \
      for (int mi = 0; mi < 4; ++mi)                                           \
          afE[mi] = *(const f16x8*)&xbp[abase[mi] + (uint32_t)((tt) * 2) * 512]; }

#define GU_LDAO(tt)                                                            \
    { _Pragma("unroll")                                                        \
      for (int mi = 0; mi < 4; ++mi)                                           \
          afO[mi] = *(const f16x8*)&xbp[abase[mi] + (uint32_t)((tt) * 2 + 1) * 512]; }

#define GU_LDQZ(k0q)                                                           \
    pw0 = *(const uint4*)(qp + (k0q));                                         \
    pw1 = *(const uint4*)(qp + (k0q) + 4);                                     \
    pz0 = *(const uint4*)(zp + (k0q));                                         \
    pz1 = *(const uint4*)(zp + (k0q) + 4);                                     \
    pz2 = *(const uint4*)(zp + HIDDEN + (k0q));                                \
    pz3 = *(const uint4*)(zp + HIDDEN + (k0q) + 4);

#define GU_DEQ(wbuf)                                                           \
    { const uint32_t wv[8] = {pw0.x, pw0.y, pw0.z, pw0.w,                      \
                              pw1.x, pw1.y, pw1.z, pw1.w};                     \
      {   const uint32_t sp[4] = {pz0.x, pz0.z, pz1.x, pz1.z};                 \
          const uint32_t np[4] = {pz0.y, pz0.w, pz1.y, pz1.w};                 \
          uint32_t o[4];                                                       \
          _Pragma("unroll")                                                    \
          for (int j = 0; j < 4; ++j)                                          \
              o[j] = deq2(wv[2*j], wv[2*j+1], sh0, sp[j], np[j]);              \
          *(uint4*)&sB[wbuf][wc0] = make_uint4(o[0], o[1], o[2], o[3]);        \
      }                                                                        \
      {   const uint32_t sp[4] = {pz2.x, pz2.z, pz3.x, pz3.z};                 \
          const uint32_t np[4] = {pz2.y, pz2.w, pz3.y, pz3.w};                 \
          uint32_t o[4];                                                       \
          _Pragma("unroll")                                                    \
          for (int j = 0; j < 4; ++j)                                          \
              o[j] = deq2(wv[2*j], wv[2*j+1], sh0 - 2u, sp[j], np[j]);         \
          *(uint4*)&sB[wbuf][wc1] = make_uint4(o[0], o[1], o[2], o[3]);        \
      } }

#define GU_MFMA(AF, rbuf, kk)                                                  \
    { const int col = ((kk) * 32 + fk) ^ sw;                                   \
      f16x8 bg0 = *(const f16x8*)&sB1[rbuf][frow * 64 + col];                  \
      f16x8 bg1 = *(const f16x8*)&sB1[rbuf][(16 + frow) * 64 + col];           \
      f16x8 bu0 = *(const f16x8*)&sB2[rbuf][frow * 64 + col];                  \
      f16x8 bu1 = *(const f16x8*)&sB2[rbuf][(16 + frow) * 64 + col];           \
      __builtin_amdgcn_s_setprio(1);                                           \
      _Pragma("unroll")                                                        \
      for (int mi = 0; mi < 4; ++mi) {                                         \
          accG[mi][0] = __builtin_amdgcn_mfma_f32_16x16x32_f16(AF[mi], bg0, accG[mi][0], 0, 0, 0); \
          accG[mi][1] = __builtin_amdgcn_mfma_f32_16x16x32_f16(AF[mi], bg1, accG[mi][1], 0, 0, 0); \
          accU[mi][0] = __builtin_amdgcn_mfma_f32_16x16x32_f16(AF[mi], bu0, accU[mi][0], 0, 0, 0); \
          accU[mi][1] = __builtin_amdgcn_mfma_f32_16x16x32_f16(AF[mi], bu1, accU[mi][1], 0, 0, 0); \
      }                                                                        \
      __builtin_amdgcn_s_setprio(0); }

    // prologue: tile0 qw/sz + A-frags; DEQ tile0 -> buf0; tile1 qw/sz in flight
    GU_LDQZ(0)
    GU_LDAE(0)
    GU_LDAO(0)
    GU_DEQ(0)
    GU_LDQZ(BK)
    LGKM_BAR()

    for (int t = 0; t < 63; ++t) {
        GU_DEQ((t + 1) & 1)               // tile t+1 (regs loaded at step t-1)
        if (t < 62) { GU_LDQZ((t + 2) * BK) }
        GU_MFMA(afE, t & 1, 0)
        GU_LDAE(t + 1)                    // refill kk0 half for next tile
        GU_MFMA(afO, t & 1, 1)
        GU_LDAO(t + 1)                    // refill kk1 half for next tile
        LGKM_BAR()
    }
    GU_MFMA(afE, 1, 0)                    // tile 63
    GU_MFMA(afO, 1, 1)

    // ---- epilogue: silu(gate)*up -> sE -> frag-major stores to hp ----
    const int rb = (lane >> 4) * 4, cb = lane & 15;
#pragma unroll
    for (int mi = 0; mi < 4; ++mi)
#pragma unroll
        for (int ni = 0; ni < 2; ++ni) {
            f32x4 g = accG[mi][ni], u = accU[mi][ni];
            const int row = wm + mi * 16 + rb;
            const int colx = ni * 16 + cb;
#pragma unroll
            for (int r = 0; r < 4; ++r) {
                float gv = g[r];
                float hv = __fdividef(gv, 1.0f + __expf(-gv)) * u[r];
                __half hh = __float2half(hv);
                sE[(row + r) * 32 + colx] = __builtin_bit_cast(ushort, hh);
            }
        }
    __syncthreads();
    {
#pragma unroll
        for (int j = 0; j < 4; ++j) {
            const int slot = tid + j * 256;
            const int mbi = slot >> 6, ls = slot & 63;
            uint4 v = *(const uint4*)&sE[(mbi * 16 + (ls & 15)) * 32 + (ls >> 4) * 8];
            *(uint4*)&hp[(size_t)(((m0 >> 4) + mbi) * KB_F + nt) * 512 + ls * 8] = v;
        }
    }
#undef GU_LDAE
#undef GU_LDAO
#undef GU_LDQZ
#undef GU_DEQ
#undef GU_MFMA
}

// ---------------- GEMM B: out_partial = hp @ w2^T (split-K = 2) ----------------
// BM=128, BN=32, BK=64, 4 waves M-stacked (wave 32x32); grid 1024 = 4 blocks/CU.

__global__ __launch_bounds__(256, 4)
void gemm_down(const ushort* __restrict__ hp, const uint32_t* __restrict__ qw2,
               const uint32_t* __restrict__ sz2, float* __restrict__ part) {
    __shared__ ushort sBd[2][32 * 64];    // 8 KB

    const int tid = threadIdx.x;
    // 1024 = 8 x 128 XCD swizzle; mt fast, sk slowest
    const int idx = ((blockIdx.x & 7) * 128) + (blockIdx.x >> 3);
    const int mt = idx & 3, nt = (idx >> 2) & 127, sk = idx >> 9;
    const int m0 = mt * 128, n0 = nt * 32;
    const int kb0 = sk * 224;             // kbeg/32
    const int kbeg = sk * (FFN / 2);

    const int lane = tid & 63, w = tid >> 6;
    const int wm = w * 32;
    const int frow = lane & 15, fk = (lane >> 4) * 8;
    const int sw = (frow & 7) << 3;

    uint32_t abase[2];
#pragma unroll
    for (int mi = 0; mi < 2; ++mi)
        abase[mi] = (uint32_t)(((m0 >> 4) + w * 2 + mi) * KB_F + kb0) * 512 + lane * 8;

    // B staging: 1 row x 8 k per thread (32 rows x 8 chunks = 256)
    const int r = tid >> 3;
    const int kc = (tid & 7) * 8;
    const int g = ((nt & 1) * 32) + r;    // (n0 + r) % 64
    const uint32_t* qp = qw2 + (size_t)(n0 / 4 + (r >> 2)) * FFN + kbeg + kc;
    const uint32_t* zp = sz2 + (size_t)g * FFN + kbeg + kc;
    const uint32_t sh = 6u - 2u * (uint32_t)(r & 3);
    const int wc = r * 64 + (kc ^ ((r & 7) << 3));

    f32x4 acc[2][2];
#pragma unroll
    for (int i = 0; i < 2; ++i)
#pragma unroll
        for (int j = 0; j < 2; ++j) acc[i][j] = (f32x4){0.f, 0.f, 0.f, 0.f};

    f16x8 afE[2], afO[2];
    uint4 pw0, pw1, pz0, pz1;

#define GD_LDAE(tt)                                                            \
    { _Pragma("unroll")                                                        \
      for (int mi = 0; mi < 2; ++mi)                                           \
          afE[mi] = *(const f16x8*)&hp[abase[mi] + (uint32_t)((tt) * 2) * 512]; }

#define GD_LDAO(tt)                                                            \
    { _Pragma("unroll")                                                        \
      for (int mi = 0; mi < 2; ++mi)                                           \
          afO[mi] = *(const f16x8*)&hp[abase[mi] + (uint32_t)((tt) * 2 + 1) * 512]; }

#define GD_LDQZ(k0q)                                                           \
    pw0 = *(const uint4*)(qp + (k0q));                                         \
    pw1 = *(const uint4*)(qp + (k0q) + 4);                                     \
    pz0 = *(const uint4*)(zp + (k0q));                                         \
    pz1 = *(const uint4*)(zp + (k0q) + 4);

#define GD_DEQ(wbuf)                                                           \
    { const uint32_t wv[8] = {pw0.x, pw0.y, pw0.z, pw0.w,                      \
                              pw1.x, pw1.y, pw1.z, pw1.w};                     \
      const uint32_t sp[4] = {pz0.x, pz0.z, pz1.x, pz1.z};                     \
      const uint32_t np[4] = {pz0.y, pz0.w, pz1.y, pz1.w};                     \
      uint32_t o[4];                                                           \
      _Pragma("unroll")                                                        \
      for (int j = 0; j < 4; ++j)                                              \
          o[j] = deq2(wv[2*j], wv[2*j+1], sh, sp[j], np[j]);                   \
      *(uint4*)&sBd[wbuf][wc] = make_uint4(o[0], o[1], o[2], o[3]); }

#define GD_MFMA(AF, rbuf, kk)                                                  \
    { const int col = ((kk) * 32 + fk) ^ sw;                                   \
      f16x8 bf0 = *(const f16x8*)&sBd[rbuf][frow * 64 + col];                  \
      f16x8 bf1 = *(const f16x8*)&sBd[rbuf][(16 + frow) * 64 + col];           \
      __builtin_amdgcn_s_setprio(1);                                           \
      _Pragma("unroll")                                                        \
      for (int mi = 0; mi < 2; ++mi) {                                         \
          acc[mi][0] = __builtin_amdgcn_mfma_f32_16x16x32_f16(AF[mi], bf0, acc[mi][0], 0, 0, 0); \
          acc[mi][1] = __builtin_amdgcn_mfma_f32_16x16x32_f16(AF[mi], bf1, acc[mi][1], 0, 0, 0); \
      }                                                                        \
      __builtin_amdgcn_s_setprio(0); }

    GD_LDQZ(0)
    GD_LDAE(0)
    GD_LDAO(0)
    GD_DEQ(0)
    GD_LDQZ(BK)
    LGKM_BAR()

    for (int t = 0; t < 111; ++t) {
        GD_DEQ((t + 1) & 1)
        if (t < 110) { GD_LDQZ((t + 2) * BK) }
        GD_MFMA(afE, t & 1, 0)
        GD_LDAE(t + 1)
        GD_MFMA(afO, t & 1, 1)
        GD_LDAO(t + 1)
        LGKM_BAR()
    }
    GD_MFMA(afE, 1, 0)                    // tile 111
    GD_MFMA(afO, 1, 1)

    float* pp = part + (size_t)sk * MDIM * HIDDEN;
    const int rb = (lane >> 4) * 4, cb = lane & 15;
#pragma unroll
    for (int mi = 0; mi < 2; ++mi)
#pragma unroll
        for (int ni = 0; ni < 2; ++ni) {
            f32x4 a = acc[mi][ni];
            const int mm = m0 + wm + mi * 16 + rb;
            const int nn = n0 + ni * 16 + cb;
#pragma unroll
            for (int rr = 0; rr < 4; ++rr) pp[(size_t)(mm + rr) * HIDDEN + nn] = a[rr];
        }
#undef GD_LDAE
#undef GD_LDAO
#undef GD_LDQZ
#undef GD_DEQ
#undef GD_MFMA
}

// ---------------- reduce split-K partials ----------------

__global__ void reduce_out(const float* __restrict__ part, float* __restrict__ out) {
    int i = blockIdx.x * blockDim.x + threadIdx.x;
    const int Q = MDIM * HIDDEN / 4;
    float4 a = ((const float4*)part)[i];
    float4 b = ((const float4*)part)[i + Q];
    float4 o;
    o.x = a.x + b.x; o.y = a.y + b.y; o.z = a.z + b.z; o.w = a.w + b.w;
    ((float4*)out)[i] = o;
}

// ---------------- launch ----------------

extern "C" void kernel_launch(void* const* d_in, const int* in_sizes, int n_in,
                              void* d_out, int out_size, void* d_ws, size_t ws_size,
                              hipStream_t stream) {
    (void)in_sizes; (void)n_in; (void)out_size; (void)ws_size;

    const float* x  = (const float*)d_in[0];
    const uint32_t* qw1 = (const uint32_t*)d_in[1];
    const float* s1 = (const float*)d_in[2];
    const float* z1 = (const float*)d_in[3];
    const uint32_t* qw3 = (const uint32_t*)d_in[4];
    const float* s3 = (const float*)d_in[5];
    const float* z3 = (const float*)d_in[6];
    const uint32_t* qw2 = (const uint32_t*)d_in[7];
    const float* s2 = (const float*)d_in[8];
    const float* z2 = (const float*)d_in[9];
    float* out = (float*)d_out;

    // ws: xbp 4.19M | sz1 3.67M | sz3 3.67M | sz2 3.67M | hp(f16) 14.68M | part 16.78M
    char* ws = (char*)d_ws;
    ushort*   xbp  = (ushort*)ws;
    uint32_t* szp1 = (uint32_t*)(ws + (size_t)MDIM * HIDDEN * 2);
    uint32_t* szp3 = szp1 + (size_t)G1 * HIDDEN;
    uint32_t* szp2 = szp3 + (size_t)G1 * HIDDEN;
    ushort*   hp   = (ushort*)(szp2 + (size_t)G2 * FFN);
    float*    part = (float*)((char*)hp + (size_t)MDIM * FFN * 2);

    cvt_xp_kernel<<<(MDIM * HIDDEN / 8) / 256, 256, 0, stream>>>(x, xbp);
    build_sz_kernel<<<(G1 * HIDDEN / 2) / 256, 256, 0, stream>>>(s1, z1, szp1);
    build_sz_kernel<<<(G1 * HIDDEN / 2) / 256, 256, 0, stream>>>(s3, z3, szp3);
    build_sz_kernel<<<(G2 * FFN / 2) / 256, 256, 0, stream>>>(s2, z2, szp2);

    gemm_gateup<<<(FFN / 32) * (MDIM / 256), 256, 0, stream>>>(xbp, qw1, szp1, qw3, szp3, hp);
    gemm_down<<<2 * (MDIM / 128) * (HIDDEN / 32), 256, 0, stream>>>(hp, qw2, szp2, part);
    reduce_out<<<(MDIM * HIDDEN / 4) / 256, 256, 0, stream>>>(part, out);
}

// Round 12
// 290.190 us; speedup vs baseline: 1.2962x; 1.1361x over previous
//
#include <hip/hip_runtime.h>
#include <hip/hip_fp16.h>
#include <stdint.h>

#define HIDDEN 4096
#define FFN    14336
#define MDIM   512
#define G1     224   // FFN / 64
#define G2     64    // HIDDEN / 64
#define BK     64
#define KB_H   128   // HIDDEN/32
#define KB_F   448   // FFN/32

typedef _Float16 f16x8 __attribute__((ext_vector_type(8)));
typedef float f32x4 __attribute__((ext_vector_type(4)));

#define SCHED0() __builtin_amdgcn_sched_barrier(0);
#define LGKM_BAR()                                            \
    asm volatile("s_waitcnt lgkmcnt(0)" ::: "memory");        \
    __builtin_amdgcn_s_barrier();                             \
    __builtin_amdgcn_sched_barrier(0);

// ---------------- prep kernels ----------------

// x (f32, row-major) -> xbp (f16, MFMA-fragment-major):
// xbp[((mb*KB_H + kb)*64 + lane)*8 + e] = x[mb*16 + (lane&15)][kb*32 + (lane>>4)*8 + e]
__global__ void cvt_xp_kernel(const float* __restrict__ x, ushort* __restrict__ xbp) {
    int i = blockIdx.x * blockDim.x + threadIdx.x;   // [0, MDIM*HIDDEN/8)
    int ls = i & 63;
    int kb = (i >> 6) & (KB_H - 1);
    int mb = i >> 13;
    int row = mb * 16 + (ls & 15);
    int col = kb * 32 + (ls >> 4) * 8;
    const float4* src = (const float4*)&x[(size_t)row * HIDDEN + col];
    float4 v0 = src[0], v1 = src[1];
    __half2 h0 = __floats2half2_rn(v0.x, v0.y);
    __half2 h1 = __floats2half2_rn(v0.z, v0.w);
    __half2 h2 = __floats2half2_rn(v1.x, v1.y);
    __half2 h3 = __floats2half2_rn(v1.z, v1.w);
    uint4 o = make_uint4(__builtin_bit_cast(uint32_t, h0), __builtin_bit_cast(uint32_t, h1),
                         __builtin_bit_cast(uint32_t, h2), __builtin_bit_cast(uint32_t, h3));
    ((uint4*)xbp)[i] = o;
}

// out[2i] = {f16(s0), f16(s1)}, out[2i+1] = {f16(-z0*s0), f16(-z1*s1)}
__global__ void build_sz_kernel(const float* __restrict__ s, const float* __restrict__ z,
                                uint32_t* __restrict__ outp) {
    int i = blockIdx.x * blockDim.x + threadIdx.x;
    float s0 = s[2 * i], s1 = s[2 * i + 1];
    float z0 = z[2 * i], z1 = z[2 * i + 1];
    __half2 hs = __floats2half2_rn(s0, s1);
    __half2 hn = __floats2half2_rn(-z0 * s0, -z1 * s1);
    ((uint2*)outp)[i] = make_uint2(__builtin_bit_cast(uint32_t, hs),
                                   __builtin_bit_cast(uint32_t, hn));
}

// dequant 2 codes -> packed f16 pair: table-select via v_perm + v_pk_fma_f16
__device__ __forceinline__ uint32_t deq2(uint32_t w0, uint32_t w1, uint32_t sh,
                                         uint32_t spair, uint32_t npair) {
    uint32_t c0 = (w0 >> sh) & 3u;
    uint32_t c1 = (w1 >> sh) & 3u;
    uint32_t sel = 0x01000100u + c0 * 0x0202u + c1 * 0x02020000u;
    uint32_t codes = __builtin_amdgcn_perm(0x42004000u, 0x3C000000u, sel); // f16{0,1,2,3}
    __half2 r = __hfma2(__builtin_bit_cast(__half2, codes),
                        __builtin_bit_cast(__half2, spair),
                        __builtin_bit_cast(__half2, npair));
    return __builtin_bit_cast(uint32_t, r);
}

// ---------------- GEMM A: gate/up fused + SwiGLU -> hp (f16 frag-major) ----------------
// BM=256, BN=32, BK=64, 4 waves M-stacked (wave 64x32). 2 tiles per barrier:
// 4 B-buffers (read pair w&1, write pair (w+1)&1), E/O qw-sz register sets,
// tile-granularity A half-set refills. 32 barriers total.

__global__ __launch_bounds__(256, 2)
void gemm_gateup(const ushort* __restrict__ xbp, const uint32_t* __restrict__ qw1,
                 const uint32_t* __restrict__ sz1, const uint32_t* __restrict__ qw3,
                 const uint32_t* __restrict__ sz3, ushort* __restrict__ hp) {
    __shared__ ushort sB1[4][32 * 64];    // 16 KB
    __shared__ ushort sB2[4][32 * 64];    // 16 KB
    __shared__ ushort sE[256 * 32];       // 16 KB epilogue staging

    const int tid = threadIdx.x;
    // XCD swizzle: 896 = 8 x 112; mt fast
    const int idx = ((blockIdx.x & 7) * 112) + (blockIdx.x >> 3);
    const int mt = idx & 1, nt = idx >> 1;
    const int m0 = mt * 256, n0 = nt * 32;

    const int lane = tid & 63, w = tid >> 6;
    const int wm = w * 64;
    const int frow = lane & 15, fk = (lane >> 4) * 8;
    const int sw = (frow & 7) << 3;       // B read-side XOR swizzle

    uint32_t abase[4];
#pragma unroll
    for (int mi = 0; mi < 4; ++mi)
        abase[mi] = (uint32_t)(((m0 >> 4) + w * 4 + mi) * KB_H) * 512 + lane * 8;

    // B staging: threads 0-127 gate, 128-255 up; 2 rows x 8 k each
    const int bi = tid & 127;
    const int rp = bi >> 3;
    const int kc = (bi & 7) * 8;
    const int row0 = rp * 2;
    const int g0 = (n0 + row0) % G1;      // even, <=222; g0+1 no wrap
    const uint32_t* qp = (tid < 128 ? qw1 : qw3) + (size_t)(n0 / 4 + (rp >> 1)) * HIDDEN + kc;
    const uint32_t* zp = (tid < 128 ? sz1 : sz3) + (size_t)g0 * HIDDEN + kc;
    ushort (*sB)[32 * 64] = (tid < 128) ? sB1 : sB2;
    const uint32_t sh0 = 6u - 4u * (uint32_t)(rp & 1);
    const int wc0 = row0 * 64 + (kc ^ ((row0 & 7) << 3));
    const int wc1 = (row0 + 1) * 64 + (kc ^ (((row0 + 1) & 7) << 3));

    f32x4 accG[4][2], accU[4][2];
#pragma unroll
    for (int i = 0; i < 4; ++i)
#pragma unroll
        for (int j = 0; j < 2; ++j) {
            accG[i][j] = (f32x4){0.f, 0.f, 0.f, 0.f};
            accU[i][j] = (f32x4){0.f, 0.f, 0.f, 0.f};
        }

    f16x8 afE[4], afO[4];                               // A half-sets (kk0/kk1)
    uint4 pwE0, pwE1, pzE0, pzE1, pzE2, pzE3;           // qw/sz set E (even tile)
    uint4 pwO0, pwO1, pzO0, pzO1, pzO2, pzO3;           // qw/sz set O (odd tile)

#define GU_LDAE(tt)                                                            \
    { _Pragma("unroll")                                                        \
      for (int mi = 0; mi < 4; ++mi)                                           \
          afE[mi] = *(const f16x8*)&xbp[abase[mi] + (uint32_t)((tt) * 2) * 512]; }

#define GU_LDAO(tt)                                                            \
    { _Pragma("unroll")                                                        \
      for (int mi = 0; mi < 4; ++mi)                                           \
          afO[mi] = *(const f16x8*)&xbp[abase[mi] + (uint32_t)((tt) * 2 + 1) * 512]; }

#define GU_LDQZ(PW0, PW1, PZ0, PZ1, PZ2, PZ3, k0q)                             \
    PW0 = *(const uint4*)(qp + (k0q));                                         \
    PW1 = *(const uint4*)(qp + (k0q) + 4);                                     \
    PZ0 = *(const uint4*)(zp + (k0q));                                         \
    PZ1 = *(const uint4*)(zp + (k0q) + 4);                                     \
    PZ2 = *(const uint4*)(zp + HIDDEN + (k0q));                                \
    PZ3 = *(const uint4*)(zp + HIDDEN + (k0q) + 4);

#define GU_DEQ(wbuf, PW0, PW1, PZ0, PZ1, PZ2, PZ3)                             \
    { const uint32_t wv[8] = {(PW0).x, (PW0).y, (PW0).z, (PW0).w,              \
                              (PW1).x, (PW1).y, (PW1).z, (PW1).w};             \
      {   const uint32_t sp[4] = {(PZ0).x, (PZ0).z, (PZ1).x, (PZ1).z};         \
          const uint32_t np[4] = {(PZ0).y, (PZ0).w, (PZ1).y, (PZ1).w};         \
          uint32_t o[4];                                                       \
          _Pragma("unroll")                                                    \
          for (int j = 0; j < 4; ++j)                                          \
              o[j] = deq2(wv[2*j], wv[2*j+1], sh0, sp[j], np[j]);              \
          *(uint4*)&sB[wbuf][wc0] = make_uint4(o[0], o[1], o[2], o[3]);        \
      }                                                                        \
      {   const uint32_t sp[4] = {(PZ2).x, (PZ2).z, (PZ3).x, (PZ3).z};         \
          const uint32_t np[4] = {(PZ2).y, (PZ2).w, (PZ3).y, (PZ3).w};         \
          uint32_t o[4];                                                       \
          _Pragma("unroll")                                                    \
          for (int j = 0; j < 4; ++j)                                          \
              o[j] = deq2(wv[2*j], wv[2*j+1], sh0 - 2u, sp[j], np[j]);         \
          *(uint4*)&sB[wbuf][wc1] = make_uint4(o[0], o[1], o[2], o[3]);        \
      } }

#define GU_MFMA(AF, rbuf, kk)                                                  \
    { const int col = ((kk) * 32 + fk) ^ sw;                                   \
      f16x8 bg0 = *(const f16x8*)&sB1[rbuf][frow * 64 + col];                  \
      f16x8 bg1 = *(const f16x8*)&sB1[rbuf][(16 + frow) * 64 + col];           \
      f16x8 bu0 = *(const f16x8*)&sB2[rbuf][frow * 64 + col];                  \
      f16x8 bu1 = *(const f16x8*)&sB2[rbuf][(16 + frow) * 64 + col];           \
      __builtin_amdgcn_s_setprio(1);                                           \
      _Pragma("unroll")                                                        \
      for (int mi = 0; mi < 4; ++mi) {                                         \
          accG[mi][0] = __builtin_amdgcn_mfma_f32_16x16x32_f16(AF[mi], bg0, accG[mi][0], 0, 0, 0); \
          accG[mi][1] = __builtin_amdgcn_mfma_f32_16x16x32_f16(AF[mi], bg1, accG[mi][1], 0, 0, 0); \
          accU[mi][0] = __builtin_amdgcn_mfma_f32_16x16x32_f16(AF[mi], bu0, accU[mi][0], 0, 0, 0); \
          accU[mi][1] = __builtin_amdgcn_mfma_f32_16x16x32_f16(AF[mi], bu1, accU[mi][1], 0, 0, 0); \
      }                                                                        \
      __builtin_amdgcn_s_setprio(0); }

// compute one tile from afE/afO against rbuf; refill halves for tile tnext
#define GU_COMPT(rbuf, tnext)                                                  \
    { GU_MFMA(afE, rbuf, 0)                                                    \
      GU_LDAE(tnext)                                                           \
      GU_MFMA(afO, rbuf, 1)                                                    \
      GU_LDAO(tnext) }

    // prologue: tiles 0,1 regs -> DEQ b0,b1; A frags tile 0; tiles 2,3 regs in flight
    GU_LDQZ(pwE0, pwE1, pzE0, pzE1, pzE2, pzE3, 0)
    GU_LDQZ(pwO0, pwO1, pzO0, pzO1, pzO2, pzO3, BK)
    GU_LDAE(0)
    GU_LDAO(0)
    GU_DEQ(0, pwE0, pwE1, pzE0, pzE1, pzE2, pzE3)
    GU_DEQ(1, pwO0, pwO1, pzO0, pzO1, pzO2, pzO3)
    GU_LDQZ(pwE0, pwE1, pzE0, pzE1, pzE2, pzE3, 2 * BK)
    GU_LDQZ(pwO0, pwO1, pzO0, pzO1, pzO2, pzO3, 3 * BK)
    LGKM_BAR()

    for (int ww = 0; ww < 31; ++ww) {
        const int rb0 = 2 * (ww & 1);               // read pair
        const int wb0 = 2 * ((ww + 1) & 1);         // write pair
        GU_DEQ(wb0,     pwE0, pwE1, pzE0, pzE1, pzE2, pzE3)   // tile 2ww+2
        GU_DEQ(wb0 + 1, pwO0, pwO1, pzO0, pzO1, pzO2, pzO3)   // tile 2ww+3
        SCHED0()
        if (ww < 30) {
            GU_LDQZ(pwE0, pwE1, pzE0, pzE1, pzE2, pzE3, (2 * ww + 4) * BK)
            GU_LDQZ(pwO0, pwO1, pzO0, pzO1, pzO2, pzO3, (2 * ww + 5) * BK)
        }
        SCHED0()
        GU_COMPT(rb0,     2 * ww + 1)               // tile 2ww
        GU_COMPT(rb0 + 1, 2 * ww + 2)               // tile 2ww+1
        LGKM_BAR()
    }
    // tiles 62,63 are in b2,b3 (written at ww=30); af holds tile 62
    GU_COMPT(2, 63)
    GU_MFMA(afE, 3, 0)
    GU_MFMA(afO, 3, 1)

    // ---- epilogue: silu(gate)*up -> sE -> frag-major stores to hp ----
    const int rb = (lane >> 4) * 4, cb = lane & 15;
#pragma unroll
    for (int mi = 0; mi < 4; ++mi)
#pragma unroll
        for (int ni = 0; ni < 2; ++ni) {
            f32x4 g = accG[mi][ni], u = accU[mi][ni];
            const int row = wm + mi * 16 + rb;
            const int colx = ni * 16 + cb;
#pragma unroll
            for (int r = 0; r < 4; ++r) {
                float gv = g[r];
                float hv = __fdividef(gv, 1.0f + __expf(-gv)) * u[r];
                __half hh = __float2half(hv);
                sE[(row + r) * 32 + colx] = __builtin_bit_cast(ushort, hh);
            }
        }
    __syncthreads();
    {
#pragma unroll
        for (int j = 0; j < 4; ++j) {
            const int slot = tid + j * 256;
            const int mbi = slot >> 6, ls = slot & 63;
            uint4 v = *(const uint4*)&sE[(mbi * 16 + (ls & 15)) * 32 + (ls >> 4) * 8];
            *(uint4*)&hp[(size_t)(((m0 >> 4) + mbi) * KB_F + nt) * 512 + ls * 8] = v;
        }
    }
#undef GU_LDAE
#undef GU_LDAO
#undef GU_LDQZ
#undef GU_DEQ
#undef GU_MFMA
#undef GU_COMPT
}

// ---------------- GEMM B: out_partial = hp @ w2^T (split-K = 2) ----------------
// BM=256, BN=32, BK=64 (R9 shape), 2 tiles per barrier; 56 barriers per half.

__global__ __launch_bounds__(256, 2)
void gemm_down(const ushort* __restrict__ hp, const uint32_t* __restrict__ qw2,
               const uint32_t* __restrict__ sz2, float* __restrict__ part) {
    __shared__ ushort sBd[4][32 * 64];    // 16 KB

    const int tid = threadIdx.x;
    // 512 = 8 x 64 XCD swizzle
    const int idx = ((blockIdx.x & 7) * 64) + (blockIdx.x >> 3);
    const int mt = idx & 1, nt = (idx >> 1) & 127, sk = idx >> 8;
    const int m0 = mt * 256, n0 = nt * 32;
    const int kb0 = sk * 224;             // kbeg/32
    const int kbeg = sk * (FFN / 2);

    const int lane = tid & 63, w = tid >> 6;
    const int wm = w * 64;
    const int frow = lane & 15, fk = (lane >> 4) * 8;
    const int sw = (frow & 7) << 3;

    uint32_t abase[4];
#pragma unroll
    for (int mi = 0; mi < 4; ++mi)
        abase[mi] = (uint32_t)(((m0 >> 4) + w * 4 + mi) * KB_F + kb0) * 512 + lane * 8;

    // B staging: 1 row x 8 k per thread (32 rows x 8 chunks = 256)
    const int r = tid >> 3;
    const int kc = (tid & 7) * 8;
    const int g = ((nt & 1) * 32) + r;    // (n0 + r) % 64
    const uint32_t* qp = qw2 + (size_t)(n0 / 4 + (r >> 2)) * FFN + kbeg + kc;
    const uint32_t* zp = sz2 + (size_t)g * FFN + kbeg + kc;
    const uint32_t sh = 6u - 2u * (uint32_t)(r & 3);
    const int wc = r * 64 + (kc ^ ((r & 7) << 3));

    f32x4 acc[4][2];
#pragma unroll
    for (int i = 0; i < 4; ++i)
#pragma unroll
        for (int j = 0; j < 2; ++j) acc[i][j] = (f32x4){0.f, 0.f, 0.f, 0.f};

    f16x8 afE[4], afO[4];
    uint4 pwE0, pwE1, pzE0, pzE1;
    uint4 pwO0, pwO1, pzO0, pzO1;

#define GD_LDAE(tt)                                                            \
    { _Pragma("unroll")                                                        \
      for (int mi = 0; mi < 4; ++mi)                                           \
          afE[mi] = *(const f16x8*)&hp[abase[mi] + (uint32_t)((tt) * 2) * 512]; }

#define GD_LDAO(tt)                                                            \
    { _Pragma("unroll")                                                        \
      for (int mi = 0; mi < 4; ++mi)                                           \
          afO[mi] = *(const f16x8*)&hp[abase[mi] + (uint32_t)((tt) * 2 + 1) * 512]; }

#define GD_LDQZ(PW0, PW1, PZ0, PZ1, k0q)                                       \
    PW0 = *(const uint4*)(qp + (k0q));                                         \
    PW1 = *(const uint4*)(qp + (k0q) + 4);                                     \
    PZ0 = *(const uint4*)(zp + (k0q));                                         \
    PZ1 = *(const uint4*)(zp + (k0q) + 4);

#define GD_DEQ(wbuf, PW0, PW1, PZ0, PZ1)                                       \
    { const uint32_t wv[8] = {(PW0).x, (PW0).y, (PW0).z, (PW0).w,              \
                              (PW1).x, (PW1).y, (PW1).z, (PW1).w};             \
      const uint32_t sp[4] = {(PZ0).x, (PZ0).z, (PZ1).x, (PZ1).z};             \
      const uint32_t np[4] = {(PZ0).y, (PZ0).w, (PZ1).y, (PZ1).w};             \
      uint32_t o[4];                                                           \
      _Pragma("unroll")                                                        \
      for (int j = 0; j < 4; ++j)                                              \
          o[j] = deq2(wv[2*j], wv[2*j+1], sh, sp[j], np[j]);                   \
      *(uint4*)&sBd[wbuf][wc] = make_uint4(o[0], o[1], o[2], o[3]); }

#define GD_MFMA(AF, rbuf, kk)                                                  \
    { const int col = ((kk) * 32 + fk) ^ sw;                                   \
      f16x8 bf0 = *(const f16x8*)&sBd[rbuf][frow * 64 + col];                  \
      f16x8 bf1 = *(const f16x8*)&sBd[rbuf][(16 + frow) * 64 + col];           \
      __builtin_amdgcn_s_setprio(1);                                           \
      _Pragma("unroll")                                                        \
      for (int mi = 0; mi < 4; ++mi) {                                         \
          acc[mi][0] = __builtin_amdgcn_mfma_f32_16x16x32_f16(AF[mi], bf0, acc[mi][0], 0, 0, 0); \
          acc[mi][1] = __builtin_amdgcn_mfma_f32_16x16x32_f16(AF[mi], bf1, acc[mi][1], 0, 0, 0); \
      }                                                                        \
      __builtin_amdgcn_s_setprio(0); }

#define GD_COMPT(rbuf, tnext)                                                  \
    { GD_MFMA(afE, rbuf, 0)                                                    \
      GD_LDAE(tnext)                                                           \
      GD_MFMA(afO, rbuf, 1)                                                    \
      GD_LDAO(tnext) }

    GD_LDQZ(pwE0, pwE1, pzE0, pzE1, 0)
    GD_LDQZ(pwO0, pwO1, pzO0, pzO1, BK)
    GD_LDAE(0)
    GD_LDAO(0)
    GD_DEQ(0, pwE0, pwE1, pzE0, pzE1)
    GD_DEQ(1, pwO0, pwO1, pzO0, pzO1)
    GD_LDQZ(pwE0, pwE1, pzE0, pzE1, 2 * BK)
    GD_LDQZ(pwO0, pwO1, pzO0, pzO1, 3 * BK)
    LGKM_BAR()

    for (int ww = 0; ww < 55; ++ww) {
        const int rb0 = 2 * (ww & 1);
        const int wb0 = 2 * ((ww + 1) & 1);
        GD_DEQ(wb0,     pwE0, pwE1, pzE0, pzE1)     // tile 2ww+2
        GD_DEQ(wb0 + 1, pwO0, pwO1, pzO0, pzO1)     // tile 2ww+3
        SCHED0()
        if (ww < 54) {
            GD_LDQZ(pwE0, pwE1, pzE0, pzE1, (2 * ww + 4) * BK)
            GD_LDQZ(pwO0, pwO1, pzO0, pzO1, (2 * ww + 5) * BK)
        }
        SCHED0()
        GD_COMPT(rb0,     2 * ww + 1)
        GD_COMPT(rb0 + 1, 2 * ww + 2)
        LGKM_BAR()
    }
    // tiles 110,111 in b2,b3; af holds tile 110
    GD_COMPT(2, 111)
    GD_MFMA(afE, 3, 0)
    GD_MFMA(afO, 3, 1)

    float* pp = part + (size_t)sk * MDIM * HIDDEN;
    const int rb = (lane >> 4) * 4, cb = lane & 15;
#pragma unroll
    for (int mi = 0; mi < 4; ++mi)
#pragma unroll
        for (int ni = 0; ni < 2; ++ni) {
            f32x4 a = acc[mi][ni];
            const int mm = m0 + wm + mi * 16 + rb;
            const int nn = n0 + ni * 16 + cb;
#pragma unroll
            for (int rr = 0; rr < 4; ++rr) pp[(size_t)(mm + rr) * HIDDEN + nn] = a[rr];
        }
#undef GD_LDAE
#undef GD_LDAO
#undef GD_LDQZ
#undef GD_DEQ
#undef GD_MFMA
#undef GD_COMPT
}

// ---------------- reduce split-K partials ----------------

__global__ void reduce_out(const float* __restrict__ part, float* __restrict__ out) {
    int i = blockIdx.x * blockDim.x + threadIdx.x;
    const int Q = MDIM * HIDDEN / 4;
    float4 a = ((const float4*)part)[i];
    float4 b = ((const float4*)part)[i + Q];
    float4 o;
    o.x = a.x + b.x; o.y = a.y + b.y; o.z = a.z + b.z; o.w = a.w + b.w;
    ((float4*)out)[i] = o;
}

// ---------------- launch ----------------

extern "C" void kernel_launch(void* const* d_in, const int* in_sizes, int n_in,
                              void* d_out, int out_size, void* d_ws, size_t ws_size,
                              hipStream_t stream) {
    (void)in_sizes; (void)n_in; (void)out_size; (void)ws_size;

    const float* x  = (const float*)d_in[0];
    const uint32_t* qw1 = (const uint32_t*)d_in[1];
    const float* s1 = (const float*)d_in[2];
    const float* z1 = (const float*)d_in[3];
    const uint32_t* qw3 = (const uint32_t*)d_in[4];
    const float* s3 = (const float*)d_in[5];
    const float* z3 = (const float*)d_in[6];
    const uint32_t* qw2 = (const uint32_t*)d_in[7];
    const float* s2 = (const float*)d_in[8];
    const float* z2 = (const float*)d_in[9];
    float* out = (float*)d_out;

    // ws: xbp 4.19M | sz1 3.67M | sz3 3.67M | sz2 3.67M | hp(f16) 14.68M | part 16.78M
    char* ws = (char*)d_ws;
    ushort*   xbp  = (ushort*)ws;
    uint32_t* szp1 = (uint32_t*)(ws + (size_t)MDIM * HIDDEN * 2);
    uint32_t* szp3 = szp1 + (size_t)G1 * HIDDEN;
    uint32_t* szp2 = szp3 + (size_t)G1 * HIDDEN;
    ushort*   hp   = (ushort*)(szp2 + (size_t)G2 * FFN);
    float*    part = (float*)((char*)hp + (size_t)MDIM * FFN * 2);

    cvt_xp_kernel<<<(MDIM * HIDDEN / 8) / 256, 256, 0, stream>>>(x, xbp);
    build_sz_kernel<<<(G1 * HIDDEN / 2) / 256, 256, 0, stream>>>(s1, z1, szp1);
    build_sz_kernel<<<(G1 * HIDDEN / 2) / 256, 256, 0, stream>>>(s3, z3, szp3);
    build_sz_kernel<<<(G2 * FFN / 2) / 256, 256, 0, stream>>>(s2, z2, szp2);

    gemm_gateup<<<(FFN / 32) * (MDIM / 256), 256, 0, stream>>>(xbp, qw1, szp1, qw3, szp3, hp);
    gemm_down<<<2 * (MDIM / 256) * (HIDDEN / 32), 256, 0, stream>>>(hp, qw2, szp2, part);
    reduce_out<<<(MDIM * HIDDEN / 4) / 256, 256, 0, stream>>>(part, out);
}